// Round 3
// baseline (1269.181 us; speedup 1.0000x reference)
//
#include <hip/hip_runtime.h>

// Problem constants (B,T,NI,NH,NO fixed by the reference)
constexpr int kB  = 64;
constexpr int kT  = 100;
constexpr int kNI = 700;
constexpr int kNH = 512;
constexpr int kNO = 20;
constexpr float TAU   = 0.6f;
constexpr float TAU_O = 0.6f;
constexpr float THR   = 0.6f;
constexpr float LR    = 0.05f;

constexpr size_t BNH = (size_t)kB * kNH;   // 32768
constexpr size_t BNI = (size_t)kB * kNI;   // 44800
constexpr size_t BNO = (size_t)kB * kNO;   // 1280

constexpr int kKP = 704;                   // padded K for xw GEMM

// Workspace layout (float offsets). PGF overlaid on XW+HSUR (dead by then).
constexpr size_t O_XW   = 0;                               // [T, t*64+b, NH]
constexpr size_t O_HSUR = O_XW   + (size_t)kT * BNH;       // [T,B,NH]
constexpr size_t O_PGF  = 0;                               // overlay: 16 x [NH,NI]
constexpr size_t O_TIN  = O_HSUR + (size_t)kT * BNH;       // [T,B,NI]
constexpr size_t O_HS   = O_TIN  + (size_t)kT * BNI;       // [T+1,B,NH] (row t = hs_{t-1})
constexpr size_t O_ERR  = O_HS   + (size_t)(kT + 1) * BNH; // [T,B,NO]
constexpr size_t O_M    = O_ERR  + (size_t)kT * BNO;       // [T,B,NH]
constexpr size_t O_TREC = O_M    + (size_t)kT * BNH;       // [T,B,NH]
constexpr size_t O_WT   = O_TREC + (size_t)kT * BNH;       // [704,NH]
constexpr size_t O_PGO  = O_WT   + (size_t)kKP * kNH;      // 8 x [NO,NH]
constexpr size_t O_PGR  = O_PGO  + 8ull * kNO * kNH;       // 16 x [NH,NH]
constexpr size_t O_MASK = O_PGR  + 16ull * kNH * kNH;      // u64 [T][B][8] = 102400 floats
constexpr size_t O_FLAG = O_MASK + 102400;                 // int  [T][B]   = 6400 floats
constexpr size_t WS_FLOATS = O_FLAG + 6400;                // ~103.1 MB

// d_out layout
constexpr size_t OUT_GF = (size_t)kB * kT * kNO;
constexpr size_t OUT_GR = OUT_GF + (size_t)kNH * kNI;
constexpr size_t OUT_GO = OUT_GR + (size_t)kNH * kNH;

// ---- w_fc1 [NH,NI] -> wT [704,NH], rows 700..703 zero -----------------------
__global__ void k_transpose(const float* __restrict__ w, float* __restrict__ wT) {
    __shared__ float tile[32][33];
    int i0 = blockIdx.x * 32, r0 = blockIdx.y * 32;
    int tx = threadIdx.x, ty = threadIdx.y; // 32 x 8
    #pragma unroll
    for (int k = 0; k < 32; k += 8) {
        int i = i0 + tx;
        tile[ty + k][tx] = (i < kNI) ? w[(size_t)(r0 + ty + k) * kNI + i] : 0.f;
    }
    __syncthreads();
    #pragma unroll
    for (int k = 0; k < 32; k += 8) {
        int i = i0 + ty + k;
        wT[(size_t)i * kNH + r0 + tx] = tile[tx][ty + k];
    }
}

// ---- tin[t,b,i] = TAU*tin[t-1] + x[b,t,i] ----------------------------------
__global__ __launch_bounds__(256) void k_tin(const float* __restrict__ x, float* __restrict__ tin) {
    int idx = blockIdx.x * 256 + threadIdx.x;
    int b = idx / kNI, i = idx % kNI;
    const float* xp = x + (size_t)b * kT * kNI + i;
    float v = 0.f;
    for (int t = 0; t < kT; t++) {
        v = TAU * v + xp[(size_t)t * kNI];
        tin[(size_t)t * BNI + idx] = v;
    }
}

// ---- XW = Xperm @ wT : C[m=t*64+b, n<512], K=704 ----------------------------
__global__ __launch_bounds__(256) void k_xw2(const float* __restrict__ x,
                                             const float* __restrict__ wT,
                                             float* __restrict__ XW) {
    int bx = blockIdx.x;
    int mt = bx % 50, nt = bx / 50;
    int m0 = mt * 128, n0 = nt * 128;
    int tid = threadIdx.x, tx = tid & 15, ty = tid >> 4;
    __shared__ float As[128][20];
    __shared__ float Bs[16][128];
    float acc[8][8] = {};
    int arow = tid >> 1, ahalf = tid & 1;
    int bb = (m0 + arow) & 63, tt = (m0 + arow) >> 6;
    const float* ap = x + ((size_t)bb * kT + tt) * kNI;
    for (int k0 = 0; k0 < kKP; k0 += 16) {
        #pragma unroll
        for (int u = 0; u < 2; u++) {
            int k = k0 + ahalf * 8 + u * 4;
            float4 v = (k + 3 < kNI) ? *(const float4*)(ap + k)
                                     : make_float4(0.f, 0.f, 0.f, 0.f);
            *(float4*)&As[arow][ahalf * 8 + u * 4] = v;
        }
        #pragma unroll
        for (int u = 0; u < 2; u++) {
            int f = tid * 2 + u;
            int kk = f >> 5, c4 = f & 31;
            *(float4*)&Bs[kk][c4 * 4] =
                *(const float4*)(wT + (size_t)(k0 + kk) * kNH + n0 + c4 * 4);
        }
        __syncthreads();
        #pragma unroll
        for (int kk = 0; kk < 16; kk++) {
            float av[8];
            #pragma unroll
            for (int i = 0; i < 4; i++) {
                av[i]     = As[ty * 4 + i][kk];
                av[4 + i] = As[64 + ty * 4 + i][kk];
            }
            float4 b0 = *(const float4*)&Bs[kk][tx * 4];
            float4 b1 = *(const float4*)&Bs[kk][64 + tx * 4];
            float bvv[8] = {b0.x, b0.y, b0.z, b0.w, b1.x, b1.y, b1.z, b1.w};
            #pragma unroll
            for (int i = 0; i < 8; i++)
                #pragma unroll
                for (int j = 0; j < 8; j++) acc[i][j] += av[i] * bvv[j];
        }
        __syncthreads();
    }
    #pragma unroll
    for (int i = 0; i < 8; i++) {
        int m = m0 + ((i < 4) ? (ty * 4 + i) : (64 + ty * 4 + i - 4));
        float* dst = XW + (size_t)m * kNH + n0;
        *(float4*)(dst + tx * 4)      = make_float4(acc[i][0], acc[i][1], acc[i][2], acc[i][3]);
        *(float4*)(dst + 64 + tx * 4) = make_float4(acc[i][4], acc[i][5], acc[i][6], acc[i][7]);
    }
}

// ---- fused forward, multi-block per sample ---------------------------------
// Blocks 0..255: hidden.  b = bx & 63, g = bx >> 6 (same-XCD grouping via %8).
//   Block owns neurons [g*128, g*128+128); 2 threads per neuron split the
//   active-j gather. Spike exchange: 8 u64 masks per (t,b) via relaxed
//   agent-scope atomics (L3-coherent, no cache invalidates -> w_rec stays in L2)
//   + release atomicAdd on flag[t][b].
// Blocks 256..319: output LIF layer for sample b = bx-256, driven by masks only.
__global__ __launch_bounds__(256) void k_fwd(float* __restrict__ ws,
                                             const float* __restrict__ label,
                                             const float* __restrict__ w_rec,
                                             const float* __restrict__ w_out,
                                             float* __restrict__ dout) {
    __shared__ float wout_ld[kNO * kNH];       // output path only (40 KB)
    __shared__ float om_ld[kNO], os_ld[kNO];
    __shared__ unsigned long long lmask[8];
    __shared__ int   list[512];
    __shared__ float partial[256];
    __shared__ int   cnt[8], bases[9];

    unsigned long long* masks = (unsigned long long*)(ws + O_MASK);
    int* flags = (int*)(ws + O_FLAG);
    int bx = blockIdx.x, tid = threadIdx.x;

    if (bx < 256) {
        // ---------------- hidden path ----------------
        int b = bx & 63, g = bx >> 6;
        int n = tid & 127, h = tid >> 7;
        const float* wr = w_rec + g * 128 + n;   // column slab
        float hm = 0.f, sp_prev = 0.f;

        for (int t = 0; t < kT; t++) {
            int nact = 0;
            if (t > 0) {
                if (tid == 0) {
                    volatile int* fp = &flags[(t - 1) * 64 + b];
                    while (__hip_atomic_load(fp, __ATOMIC_RELAXED, __HIP_MEMORY_SCOPE_AGENT) < 4) {}
                }
                __syncthreads();
                if (tid < 8) {
                    unsigned long long m = __hip_atomic_load(
                        &masks[((size_t)(t - 1) * 64 + b) * 8 + tid],
                        __ATOMIC_RELAXED, __HIP_MEMORY_SCOPE_AGENT);
                    lmask[tid] = m;
                    cnt[tid] = __popcll(m);
                }
                __syncthreads();
                if (tid == 0) {
                    int s = 0;
                    #pragma unroll
                    for (int i = 0; i < 8; i++) { bases[i] = s; s += cnt[i]; }
                    bases[8] = s;
                }
                __syncthreads();
                nact = bases[8];
                // parallel ordered list build: this thread handles j=tid, j=tid+256
                #pragma unroll
                for (int u = 0; u < 2; u++) {
                    int j = tid + u * 256;
                    unsigned long long m = lmask[j >> 6];
                    int bit = j & 63;
                    if ((m >> bit) & 1) {
                        int pos = bases[j >> 6] + __popcll(m & (((unsigned long long)1 << bit) - 1));
                        list[pos] = j;
                    }
                }
                __syncthreads();
            }
            // gather: half h of the active list
            float rec = 0.f;
            if (nact > 0) {
                int nhalf = nact >> 1;
                int lo = h ? nhalf : 0;
                int hi = h ? nact : nhalf;
                int i = lo;
                for (; i + 8 <= hi; i += 8) {
                    float v[8];
                    #pragma unroll
                    for (int u = 0; u < 8; u++) v[u] = wr[(size_t)list[i + u] * kNH];
                    #pragma unroll
                    for (int u = 0; u < 8; u++) rec += v[u];
                }
                for (; i < hi; i++) rec += wr[(size_t)list[i] * kNH];
            }
            partial[tid] = rec;
            __syncthreads();
            if (tid < 128) {
                float rtot = partial[tid] + partial[tid + 128];
                float xw = ws[O_XW + ((size_t)t * 64 + b) * kNH + g * 128 + n];
                hm = TAU * hm * (1.f - sp_prev) + (xw + rtot);
                bool v = (hm >= THR);
                float sp = v ? 1.f : 0.f;
                sp_prev = sp;
                size_t hso = O_HS + (size_t)(t + 1) * BNH + (size_t)b * kNH + g * 128 + n;
                ws[hso] = sp;
                ws[O_HSUR + (size_t)t * BNH + (size_t)b * kNH + g * 128 + n] =
                    TAU * fmaxf(0.f, 1.f - fabsf(hm - THR) * (1.f / THR));
                unsigned long long bal = __ballot(v);   // per-wave (64 lanes)
                if ((tid & 63) == 0) {
                    int w = tid >> 6;   // 0 or 1
                    __hip_atomic_store(&masks[((size_t)t * 64 + b) * 8 + g * 2 + w], bal,
                                       __ATOMIC_RELAXED, __HIP_MEMORY_SCOPE_AGENT);
                }
            }
            __syncthreads();   // drains vmcnt: mask stores complete before flag
            if (tid == 0)
                __hip_atomic_fetch_add(&flags[t * 64 + b], 1,
                                       __ATOMIC_RELEASE, __HIP_MEMORY_SCOPE_AGENT);
        }
    } else {
        // ---------------- output path ----------------
        int b = bx - 256;
        for (int e = tid; e < kNO * kNH; e += 256) wout_ld[e] = w_out[e];
        if (tid < kNO) { om_ld[tid] = 0.f; os_ld[tid] = 0.f; }
        int lane = tid & 63, w = tid >> 6;
        __syncthreads();
        for (int t = 0; t < kT; t++) {
            if (tid == 0) {
                volatile int* fp = &flags[t * 64 + b];
                while (__hip_atomic_load(fp, __ATOMIC_RELAXED, __HIP_MEMORY_SCOPE_AGENT) < 4)
                    __builtin_amdgcn_s_sleep(1);
            }
            __syncthreads();
            if (tid < 8)
                lmask[tid] = __hip_atomic_load(&masks[((size_t)t * 64 + b) * 8 + tid],
                                               __ATOMIC_RELAXED, __HIP_MEMORY_SCOPE_AGENT);
            __syncthreads();
            #pragma unroll
            for (int q = 0; q < 5; q++) {
                int o = w * 5 + q;
                float p = 0.f;
                #pragma unroll
                for (int k = 0; k < 8; k++)
                    if ((lmask[k] >> lane) & 1) p += wout_ld[o * kNH + 64 * k + lane];
                #pragma unroll
                for (int off = 32; off >= 1; off >>= 1) p += __shfl_xor(p, off);
                if (lane == 0) {
                    float om = om_ld[o], os = os_ld[o];
                    float om_n = TAU * om * (1.f - os) + p;
                    float os_n = (om_n >= THR) ? 1.f : 0.f;
                    om_ld[o] = om_n; os_ld[o] = os_n;
                    ws[O_ERR + (size_t)t * BNO + (size_t)b * kNO + o] =
                        os_n - label[((size_t)b * kT + t) * kNO + o];
                    dout[((size_t)b * kT + t) * kNO + o] = os_n;
                }
            }
        }
    }
}

// ---- reverse kappa filter of err (in place) --------------------------------
__global__ void k_errscan(float* __restrict__ ws) {
    int idx = blockIdx.x * 256 + threadIdx.x;  // < 1280
    float v = 0.f;
    for (int t = kT - 1; t >= 0; t--) {
        float* p = ws + O_ERR + (size_t)t * BNO + idx;
        v = *p + TAU_O * v;
        *p = v;
    }
}

// ---- M[tb,r] = LR * (errf[tb,:] @ w_out)[r] * hsur[tb,r] --------------------
__global__ __launch_bounds__(256) void k_M(float* __restrict__ ws, const float* __restrict__ w_out) {
    __shared__ float wo[kNO * kNH];
    __shared__ float ef[8 * kNO];
    int tid = threadIdx.x;
    int tb0 = blockIdx.x * 8;
    for (int e = tid; e < kNO * kNH; e += 256) wo[e] = w_out[e];
    for (int e = tid; e < 8 * kNO; e += 256) ef[e] = ws[O_ERR + (size_t)tb0 * kNO + e];
    __syncthreads();
    for (int e = tid; e < 8 * kNH; e += 256) {
        int tbl = e >> 9, r = e & 511;
        float s = 0.f;
        #pragma unroll
        for (int o = 0; o < kNO; o++) s += ef[tbl * kNO + o] * wo[o * kNH + r];
        size_t g = (size_t)(tb0 + tbl) * kNH + r;
        ws[O_M + g] = LR * s * ws[O_HSUR + g];
    }
}

// ---- trec[t,b,j] = TAU*trec[t-1] + hs_{t-1} --------------------------------
__global__ void k_trec(float* __restrict__ ws) {
    size_t idx = (size_t)blockIdx.x * 256 + threadIdx.x;  // < BNH
    float v = 0.f;
    for (int t = 0; t < kT; t++) {
        v = TAU * v + ws[O_HS + (size_t)t * BNH + idx];
        ws[O_TREC + (size_t)t * BNH + idx] = v;
    }
}

// ---- TN GEMM 128x128x(Kc=400), 8x8/thread, 16 K-slices ----------------------
__global__ __launch_bounds__(256) void k_gemm_tn(const float* __restrict__ A,
                                                 const float* __restrict__ Bm,
                                                 float* __restrict__ Cpart,
                                                 int Ndim) {
    int bx = blockIdx.x;
    int s = bx & 15, tmp = bx >> 4;
    int mt = tmp & 3, nt = tmp >> 2;
    int m0 = mt * 128, n0 = nt * 128;
    int k0 = s * 400;
    int tid = threadIdx.x, tx = tid & 15, ty = tid >> 4;
    __shared__ float As[16][128];
    __shared__ float Bs[16][128];
    float acc[8][8] = {};
    for (int kb = 0; kb < 400; kb += 16) {
        #pragma unroll
        for (int u = 0; u < 2; u++) {
            int f = tid * 2 + u;
            int kk = f >> 5, c4 = f & 31;
            size_t gk = (size_t)(k0 + kb + kk);
            *(float4*)&As[kk][c4 * 4] = *(const float4*)(A + gk * kNH + m0 + c4 * 4);
            int n = n0 + c4 * 4;
            *(float4*)&Bs[kk][c4 * 4] = (n < Ndim) ? *(const float4*)(Bm + gk * Ndim + n)
                                                   : make_float4(0.f, 0.f, 0.f, 0.f);
        }
        __syncthreads();
        #pragma unroll
        for (int kk = 0; kk < 16; kk++) {
            float4 a0 = *(const float4*)&As[kk][ty * 4];
            float4 a1 = *(const float4*)&As[kk][64 + ty * 4];
            float4 b0 = *(const float4*)&Bs[kk][tx * 4];
            float4 b1 = *(const float4*)&Bs[kk][64 + tx * 4];
            float av[8] = {a0.x, a0.y, a0.z, a0.w, a1.x, a1.y, a1.z, a1.w};
            float bv[8] = {b0.x, b0.y, b0.z, b0.w, b1.x, b1.y, b1.z, b1.w};
            #pragma unroll
            for (int i = 0; i < 8; i++)
                #pragma unroll
                for (int j = 0; j < 8; j++) acc[i][j] += av[i] * bv[j];
        }
        __syncthreads();
    }
    float* C = Cpart + (size_t)s * kNH * Ndim;
    #pragma unroll
    for (int i = 0; i < 8; i++) {
        int m = m0 + ((i < 4) ? (ty * 4 + i) : (64 + ty * 4 + i - 4));
        float* dst = C + (size_t)m * Ndim;
        int n = n0 + tx * 4;
        if (n < Ndim)
            *(float4*)(dst + n) = make_float4(acc[i][0], acc[i][1], acc[i][2], acc[i][3]);
        if (n + 64 < Ndim)
            *(float4*)(dst + n + 64) = make_float4(acc[i][4], acc[i][5], acc[i][6], acc[i][7]);
    }
}

// ---- small TN GEMM for go (M=20) -------------------------------------------
__global__ __launch_bounds__(256) void k_gemmTN_go(const float* __restrict__ A,
                                                   const float* __restrict__ Bm,
                                                   float* __restrict__ Cpart) {
    int bx = blockIdx.x, tid = threadIdx.x;  // grid 64 = 8 s * 8 nt
    int s = bx & 7, nt = bx >> 3;
    int n0 = nt * 64, k0 = s * 800;
    __shared__ float As[16][64];
    __shared__ float Bs[16][64];
    int tx = tid & 15, ty = tid >> 4;
    float acc[4][4] = {};
    for (int kb = 0; kb < 800; kb += 16) {
        #pragma unroll
        for (int e = tid; e < 1024; e += 256) {
            int kk = e >> 6, c = e & 63;
            size_t gk = (size_t)(k0 + kb + kk);
            As[kk][c] = (c < kNO) ? A[gk * kNO + c] : 0.f;
            Bs[kk][c] = Bm[gk * kNH + n0 + c];
        }
        __syncthreads();
        #pragma unroll
        for (int kk = 0; kk < 16; kk++) {
            float4 av = *(const float4*)&As[kk][ty * 4];
            float4 bv = *(const float4*)&Bs[kk][tx * 4];
            float aa[4] = {av.x, av.y, av.z, av.w};
            float bb[4] = {bv.x, bv.y, bv.z, bv.w};
            #pragma unroll
            for (int a = 0; a < 4; a++)
                #pragma unroll
                for (int c = 0; c < 4; c++) acc[a][c] += aa[a] * bb[c];
        }
        __syncthreads();
    }
    float* Cs = Cpart + (size_t)s * kNO * kNH;
    #pragma unroll
    for (int a = 0; a < 4; a++) {
        int m = ty * 4 + a;
        if (m >= kNO) continue;
        #pragma unroll
        for (int c = 0; c < 4; c++)
            Cs[(size_t)m * kNH + n0 + tx * 4 + c] = acc[a][c];
    }
}

// ---- reductions -------------------------------------------------------------
__global__ void k_reduce_gfgr(const float* __restrict__ ws, float* __restrict__ dout) {
    int idx = blockIdx.x * 256 + threadIdx.x;  // < 620544
    const int NGF = kNH * kNI, NGR = kNH * kNH;
    float s = 0.f;
    if (idx < NGF) {
        #pragma unroll
        for (int k = 0; k < 16; k++) s += ws[O_PGF + (size_t)k * NGF + idx];
        dout[OUT_GF + idx] = s;   // LR folded into M
    } else {
        int j = idx - NGF;
        #pragma unroll
        for (int k = 0; k < 16; k++) s += ws[O_PGR + (size_t)k * NGR + j];
        dout[OUT_GR + j] = s;
    }
}

__global__ void k_reduce_go(const float* __restrict__ ws, float* __restrict__ dout) {
    int idx = blockIdx.x * 256 + threadIdx.x;  // < 10240
    const int NGO = kNO * kNH;
    float s = 0.f;
    #pragma unroll
    for (int k = 0; k < 8; k++) s += ws[O_PGO + (size_t)k * NGO + idx];
    dout[OUT_GO + idx] = LR * s;
}

extern "C" void kernel_launch(void* const* d_in, const int* in_sizes, int n_in,
                              void* d_out, int out_size, void* d_ws, size_t ws_size,
                              hipStream_t stream) {
    (void)in_sizes; (void)n_in; (void)out_size;
    const float* x     = (const float*)d_in[0];
    const float* label = (const float*)d_in[1];
    const float* w_fc1 = (const float*)d_in[3];
    const float* w_rec = (const float*)d_in[4];
    const float* w_out = (const float*)d_in[5];
    float* out = (float*)d_out;
    float* ws  = (float*)d_ws;

    if (ws_size < WS_FLOATS * sizeof(float)) return;

    // hs row 0 (= hs_{-1}) zero for trec scan; masks+flags zero for sync protocol
    hipMemsetAsync(ws + O_HS, 0, BNH * sizeof(float), stream);
    hipMemsetAsync(ws + O_MASK, 0, (102400 + 6400) * sizeof(float), stream);

    k_transpose<<<dim3(22, 16), dim3(32, 8), 0, stream>>>(w_fc1, ws + O_WT);
    k_tin<<<175, 256, 0, stream>>>(x, ws + O_TIN);
    k_xw2<<<200, 256, 0, stream>>>(x, ws + O_WT, ws + O_XW);

    k_fwd<<<320, 256, 0, stream>>>(ws, label, w_rec, w_out, out);

    k_errscan<<<5, 256, 0, stream>>>(ws);
    k_M<<<kT * kB / 8, 256, 0, stream>>>(ws, w_out);
    k_trec<<<128, 256, 0, stream>>>(ws);

    const int K = kT * kB;  (void)K;
    k_gemm_tn<<<16 * 4 * 6, 256, 0, stream>>>(ws + O_M, ws + O_TIN, ws + O_PGF, kNI);
    k_gemm_tn<<<16 * 4 * 4, 256, 0, stream>>>(ws + O_M, ws + O_TREC, ws + O_PGR, kNH);
    k_gemmTN_go<<<64, 256, 0, stream>>>(ws + O_ERR, ws + O_HS + BNH, ws + O_PGO);

    k_reduce_gfgr<<<2424, 256, 0, stream>>>(ws, out);
    k_reduce_go<<<40, 256, 0, stream>>>(ws, out);
}

// Round 4
// 1008.074 us; speedup vs baseline: 1.2590x; 1.2590x over previous
//
#include <hip/hip_runtime.h>

// Problem constants (B,T,NI,NH,NO fixed by the reference)
constexpr int kB  = 64;
constexpr int kT  = 100;
constexpr int kNI = 700;
constexpr int kNH = 512;
constexpr int kNO = 20;
constexpr float TAU   = 0.6f;
constexpr float TAU_O = 0.6f;
constexpr float THR   = 0.6f;
constexpr float LR    = 0.05f;

constexpr size_t BNH = (size_t)kB * kNH;   // 32768
constexpr size_t BNI = (size_t)kB * kNI;   // 44800
constexpr size_t BNO = (size_t)kB * kNO;   // 1280

constexpr int kKP = 704;                   // padded K for xw GEMM

// Workspace layout (float offsets). PGF overlaid on XW+HSUR (dead by then).
constexpr size_t O_XW   = 0;                               // [T, t*64+b, NH]
constexpr size_t O_HSUR = O_XW   + (size_t)kT * BNH;       // [T,B,NH]
constexpr size_t O_PGF  = 0;                               // overlay: 16 x [NH,NI]
constexpr size_t O_TIN  = O_HSUR + (size_t)kT * BNH;       // [T,B,NI]
constexpr size_t O_HS   = O_TIN  + (size_t)kT * BNI;       // [T+1,B,NH] (row t = hs_{t-1})
constexpr size_t O_ERR  = O_HS   + (size_t)(kT + 1) * BNH; // [T,B,NO]
constexpr size_t O_M    = O_ERR  + (size_t)kT * BNO;       // [T,B,NH]
constexpr size_t O_TREC = O_M    + (size_t)kT * BNH;       // [T,B,NH]
constexpr size_t O_WT   = O_TREC + (size_t)kT * BNH;       // [704,NH]
constexpr size_t O_PGO  = O_WT   + (size_t)kKP * kNH;      // 8 x [NO,NH]
constexpr size_t O_PGR  = O_PGO  + 8ull * kNO * kNH;       // 16 x [NH,NH]
constexpr size_t WS_FLOATS = O_PGR + 16ull * kNH * kNH;

// d_out layout
constexpr size_t OUT_GF = (size_t)kB * kT * kNO;
constexpr size_t OUT_GR = OUT_GF + (size_t)kNH * kNI;
constexpr size_t OUT_GO = OUT_GR + (size_t)kNH * kNH;

// ---- w_fc1 [NH,NI] -> wT [704,NH], rows 700..703 zero -----------------------
__global__ void k_transpose(const float* __restrict__ w, float* __restrict__ wT) {
    __shared__ float tile[32][33];
    int i0 = blockIdx.x * 32, r0 = blockIdx.y * 32;
    int tx = threadIdx.x, ty = threadIdx.y; // 32 x 8
    #pragma unroll
    for (int k = 0; k < 32; k += 8) {
        int i = i0 + tx;
        tile[ty + k][tx] = (i < kNI) ? w[(size_t)(r0 + ty + k) * kNI + i] : 0.f;
    }
    __syncthreads();
    #pragma unroll
    for (int k = 0; k < 32; k += 8) {
        int i = i0 + ty + k;
        wT[(size_t)i * kNH + r0 + tx] = tile[tx][ty + k];
    }
}

// ---- tin[t,b,i] = TAU*tin[t-1] + x[b,t,i] ----------------------------------
__global__ __launch_bounds__(256) void k_tin(const float* __restrict__ x, float* __restrict__ tin) {
    int idx = blockIdx.x * 256 + threadIdx.x;
    int b = idx / kNI, i = idx % kNI;
    const float* xp = x + (size_t)b * kT * kNI + i;
    float v = 0.f;
    for (int t = 0; t < kT; t++) {
        v = TAU * v + xp[(size_t)t * kNI];
        tin[(size_t)t * BNI + idx] = v;
    }
}

// ---- XW = Xperm @ wT : C[m=t*64+b, n<512], K=704 ----------------------------
__global__ __launch_bounds__(256) void k_xw2(const float* __restrict__ x,
                                             const float* __restrict__ wT,
                                             float* __restrict__ XW) {
    int bx = blockIdx.x;
    int mt = bx % 50, nt = bx / 50;
    int m0 = mt * 128, n0 = nt * 128;
    int tid = threadIdx.x, tx = tid & 15, ty = tid >> 4;
    __shared__ float As[128][20];
    __shared__ float Bs[16][128];
    float acc[8][8] = {};
    int arow = tid >> 1, ahalf = tid & 1;
    int bb = (m0 + arow) & 63, tt = (m0 + arow) >> 6;
    const float* ap = x + ((size_t)bb * kT + tt) * kNI;
    for (int k0 = 0; k0 < kKP; k0 += 16) {
        #pragma unroll
        for (int u = 0; u < 2; u++) {
            int k = k0 + ahalf * 8 + u * 4;
            float4 v = (k + 3 < kNI) ? *(const float4*)(ap + k)
                                     : make_float4(0.f, 0.f, 0.f, 0.f);
            *(float4*)&As[arow][ahalf * 8 + u * 4] = v;
        }
        #pragma unroll
        for (int u = 0; u < 2; u++) {
            int f = tid * 2 + u;
            int kk = f >> 5, c4 = f & 31;
            *(float4*)&Bs[kk][c4 * 4] =
                *(const float4*)(wT + (size_t)(k0 + kk) * kNH + n0 + c4 * 4);
        }
        __syncthreads();
        #pragma unroll
        for (int kk = 0; kk < 16; kk++) {
            float av[8];
            #pragma unroll
            for (int i = 0; i < 4; i++) {
                av[i]     = As[ty * 4 + i][kk];
                av[4 + i] = As[64 + ty * 4 + i][kk];
            }
            float4 b0 = *(const float4*)&Bs[kk][tx * 4];
            float4 b1 = *(const float4*)&Bs[kk][64 + tx * 4];
            float bvv[8] = {b0.x, b0.y, b0.z, b0.w, b1.x, b1.y, b1.z, b1.w};
            #pragma unroll
            for (int i = 0; i < 8; i++)
                #pragma unroll
                for (int j = 0; j < 8; j++) acc[i][j] += av[i] * bvv[j];
        }
        __syncthreads();
    }
    #pragma unroll
    for (int i = 0; i < 8; i++) {
        int m = m0 + ((i < 4) ? (ty * 4 + i) : (64 + ty * 4 + i - 4));
        float* dst = XW + (size_t)m * kNH + n0;
        *(float4*)(dst + tx * 4)      = make_float4(acc[i][0], acc[i][1], acc[i][2], acc[i][3]);
        *(float4*)(dst + 64 + tx * 4) = make_float4(acc[i][4], acc[i][5], acc[i][6], acc[i][7]);
    }
}

// ---- fused forward: ONE block of 1024 threads per sample --------------------
// Phase A: all 16 waves gather active w_rec rows, 8-way list split, float4/lane.
// Phase B: threads<512 reduce partials + LIF update + ballot masks into LDS.
// Phase C: threads<512 build next active list; waves 8..12 run the output LIF
//          layer off the masks concurrently. 3 __syncthreads per step.
__global__ __launch_bounds__(1024) void k_forward(float* __restrict__ ws,
                                                  const float* __restrict__ label,
                                                  const float* __restrict__ w_rec,
                                                  const float* __restrict__ w_out,
                                                  float* __restrict__ dout) {
    __shared__ float wout_ld[kNO * kNH];   // 40 KB
    __shared__ float partial[8][kNH];      // 16 KB
    __shared__ int   list[kNH];
    __shared__ unsigned long long lmask[2][8];
    __shared__ int   cnt[8];
    __shared__ float om_ld[kNO], os_ld[kNO];

    int b = blockIdx.x, tid = threadIdx.x;
    int c4 = tid & 127, sh = tid >> 7;     // float4 column / list share
    const float4* wr4 = (const float4*)w_rec;
    for (int e = tid; e < kNO * kNH; e += 1024) wout_ld[e] = w_out[e];
    if (tid < kNO) { om_ld[tid] = 0.f; os_ld[tid] = 0.f; }
    float hm = 0.f, sp_prev = 0.f;
    int nact = 0;
    __syncthreads();

    for (int t = 0; t < kT; t++) {
        // ---- A: gather (list holds active j of step t-1) ----
        float xw = 0.f;
        if (tid < kNH) xw = ws[O_XW + ((size_t)t * 64 + b) * kNH + tid];
        float4 a0 = make_float4(0.f, 0.f, 0.f, 0.f), a1 = a0, a2 = a0, a3 = a0;
        int i = sh;
        for (; i + 24 < nact; i += 32) {
            int j0 = list[i], j1 = list[i + 8], j2 = list[i + 16], j3 = list[i + 24];
            float4 v0 = wr4[(size_t)j0 * 128 + c4];
            float4 v1 = wr4[(size_t)j1 * 128 + c4];
            float4 v2 = wr4[(size_t)j2 * 128 + c4];
            float4 v3 = wr4[(size_t)j3 * 128 + c4];
            a0.x += v0.x; a0.y += v0.y; a0.z += v0.z; a0.w += v0.w;
            a1.x += v1.x; a1.y += v1.y; a1.z += v1.z; a1.w += v1.w;
            a2.x += v2.x; a2.y += v2.y; a2.z += v2.z; a2.w += v2.w;
            a3.x += v3.x; a3.y += v3.y; a3.z += v3.z; a3.w += v3.w;
        }
        for (; i < nact; i += 8) {
            float4 v = wr4[(size_t)list[i] * 128 + c4];
            a0.x += v.x; a0.y += v.y; a0.z += v.z; a0.w += v.w;
        }
        a0.x += a1.x + a2.x + a3.x; a0.y += a1.y + a2.y + a3.y;
        a0.z += a1.z + a2.z + a3.z; a0.w += a1.w + a2.w + a3.w;
        *(float4*)&partial[sh][c4 * 4] = a0;
        __syncthreads();
        // ---- B: LIF update (threads < 512, one neuron each) ----
        if (tid < kNH) {
            float rec = ((partial[0][tid] + partial[1][tid]) + (partial[2][tid] + partial[3][tid]))
                      + ((partial[4][tid] + partial[5][tid]) + (partial[6][tid] + partial[7][tid]));
            hm = TAU * hm * (1.f - sp_prev) + (xw + rec);
            bool v = (hm >= THR);
            float sp = v ? 1.f : 0.f;
            sp_prev = sp;
            ws[O_HS + (size_t)(t + 1) * BNH + (size_t)b * kNH + tid] = sp;
            ws[O_HSUR + (size_t)t * BNH + (size_t)b * kNH + tid] =
                TAU * fmaxf(0.f, 1.f - fabsf(hm - THR) * (1.f / THR));
            unsigned long long bal = __ballot(v);   // waves 0..7 fully active here
            if ((tid & 63) == 0) {
                int w = tid >> 6;
                lmask[t & 1][w] = bal;
                cnt[w] = __popcll(bal);
            }
        }
        __syncthreads();
        // ---- C: next list build (threads<512) || output layer (waves 8..12) ----
        int bases[8], tot = 0;
        #pragma unroll
        for (int k = 0; k < 8; k++) { bases[k] = tot; tot += cnt[k]; }
        nact = tot;
        if (tid < kNH) {
            unsigned long long m = lmask[t & 1][tid >> 6];
            int bit = tid & 63;
            if ((m >> bit) & 1)
                list[bases[tid >> 6] + __popcll(m & (((unsigned long long)1 << bit) - 1ull))] = tid;
        } else {
            int u = tid - kNH, lane = u & 63, q = u >> 6;
            if (q < 5) {
                #pragma unroll
                for (int r = 0; r < 4; r++) {
                    int o = q * 4 + r;
                    float p = 0.f;
                    #pragma unroll
                    for (int k = 0; k < 8; k++)
                        if ((lmask[t & 1][k] >> lane) & 1) p += wout_ld[o * kNH + 64 * k + lane];
                    #pragma unroll
                    for (int off = 32; off >= 1; off >>= 1) p += __shfl_xor(p, off);
                    if (lane == 0) {
                        float om = om_ld[o], os = os_ld[o];
                        float om_n = TAU * om * (1.f - os) + p;
                        float os_n = (om_n >= THR) ? 1.f : 0.f;
                        om_ld[o] = om_n; os_ld[o] = os_n;
                        ws[O_ERR + (size_t)t * BNO + (size_t)b * kNO + o] =
                            os_n - label[((size_t)b * kT + t) * kNO + o];
                        dout[((size_t)b * kT + t) * kNO + o] = os_n;
                    }
                }
            }
        }
        __syncthreads();
    }
}

// ---- reverse kappa filter of err (in place) --------------------------------
__global__ void k_errscan(float* __restrict__ ws) {
    int idx = blockIdx.x * 256 + threadIdx.x;  // < 1280
    float v = 0.f;
    for (int t = kT - 1; t >= 0; t--) {
        float* p = ws + O_ERR + (size_t)t * BNO + idx;
        v = *p + TAU_O * v;
        *p = v;
    }
}

// ---- M[tb,r] = LR * (errf[tb,:] @ w_out)[r] * hsur[tb,r] --------------------
__global__ __launch_bounds__(256) void k_M(float* __restrict__ ws, const float* __restrict__ w_out) {
    __shared__ float wo[kNO * kNH];
    __shared__ float ef[8 * kNO];
    int tid = threadIdx.x;
    int tb0 = blockIdx.x * 8;
    for (int e = tid; e < kNO * kNH; e += 256) wo[e] = w_out[e];
    for (int e = tid; e < 8 * kNO; e += 256) ef[e] = ws[O_ERR + (size_t)tb0 * kNO + e];
    __syncthreads();
    for (int e = tid; e < 8 * kNH; e += 256) {
        int tbl = e >> 9, r = e & 511;
        float s = 0.f;
        #pragma unroll
        for (int o = 0; o < kNO; o++) s += ef[tbl * kNO + o] * wo[o * kNH + r];
        size_t g = (size_t)(tb0 + tbl) * kNH + r;
        ws[O_M + g] = LR * s * ws[O_HSUR + g];
    }
}

// ---- trec[t,b,j] = TAU*trec[t-1] + hs_{t-1} --------------------------------
__global__ void k_trec(float* __restrict__ ws) {
    size_t idx = (size_t)blockIdx.x * 256 + threadIdx.x;  // < BNH
    float v = 0.f;
    for (int t = 0; t < kT; t++) {
        v = TAU * v + ws[O_HS + (size_t)t * BNH + idx];
        ws[O_TREC + (size_t)t * BNH + idx] = v;
    }
}

// ---- TN GEMM 128x128x(Kc=400), 8x8/thread, 16 K-slices ----------------------
__global__ __launch_bounds__(256) void k_gemm_tn(const float* __restrict__ A,
                                                 const float* __restrict__ Bm,
                                                 float* __restrict__ Cpart,
                                                 int Ndim) {
    int bx = blockIdx.x;
    int s = bx & 15, tmp = bx >> 4;
    int mt = tmp & 3, nt = tmp >> 2;
    int m0 = mt * 128, n0 = nt * 128;
    int k0 = s * 400;
    int tid = threadIdx.x, tx = tid & 15, ty = tid >> 4;
    __shared__ float As[16][128];
    __shared__ float Bs[16][128];
    float acc[8][8] = {};
    for (int kb = 0; kb < 400; kb += 16) {
        #pragma unroll
        for (int u = 0; u < 2; u++) {
            int f = tid * 2 + u;
            int kk = f >> 5, c4 = f & 31;
            size_t gk = (size_t)(k0 + kb + kk);
            *(float4*)&As[kk][c4 * 4] = *(const float4*)(A + gk * kNH + m0 + c4 * 4);
            int n = n0 + c4 * 4;
            *(float4*)&Bs[kk][c4 * 4] = (n < Ndim) ? *(const float4*)(Bm + gk * Ndim + n)
                                                   : make_float4(0.f, 0.f, 0.f, 0.f);
        }
        __syncthreads();
        #pragma unroll
        for (int kk = 0; kk < 16; kk++) {
            float4 a0 = *(const float4*)&As[kk][ty * 4];
            float4 a1 = *(const float4*)&As[kk][64 + ty * 4];
            float4 b0 = *(const float4*)&Bs[kk][tx * 4];
            float4 b1 = *(const float4*)&Bs[kk][64 + tx * 4];
            float av[8] = {a0.x, a0.y, a0.z, a0.w, a1.x, a1.y, a1.z, a1.w};
            float bv[8] = {b0.x, b0.y, b0.z, b0.w, b1.x, b1.y, b1.z, b1.w};
            #pragma unroll
            for (int i = 0; i < 8; i++)
                #pragma unroll
                for (int j = 0; j < 8; j++) acc[i][j] += av[i] * bv[j];
        }
        __syncthreads();
    }
    float* C = Cpart + (size_t)s * kNH * Ndim;
    #pragma unroll
    for (int i = 0; i < 8; i++) {
        int m = m0 + ((i < 4) ? (ty * 4 + i) : (64 + ty * 4 + i - 4));
        float* dst = C + (size_t)m * Ndim;
        int n = n0 + tx * 4;
        if (n < Ndim)
            *(float4*)(dst + n) = make_float4(acc[i][0], acc[i][1], acc[i][2], acc[i][3]);
        if (n + 64 < Ndim)
            *(float4*)(dst + n + 64) = make_float4(acc[i][4], acc[i][5], acc[i][6], acc[i][7]);
    }
}

// ---- small TN GEMM for go (M=20) -------------------------------------------
__global__ __launch_bounds__(256) void k_gemmTN_go(const float* __restrict__ A,
                                                   const float* __restrict__ Bm,
                                                   float* __restrict__ Cpart) {
    int bx = blockIdx.x, tid = threadIdx.x;  // grid 64 = 8 s * 8 nt
    int s = bx & 7, nt = bx >> 3;
    int n0 = nt * 64, k0 = s * 800;
    __shared__ float As[16][64];
    __shared__ float Bs[16][64];
    int tx = tid & 15, ty = tid >> 4;
    float acc[4][4] = {};
    for (int kb = 0; kb < 800; kb += 16) {
        #pragma unroll
        for (int e = tid; e < 1024; e += 256) {
            int kk = e >> 6, c = e & 63;
            size_t gk = (size_t)(k0 + kb + kk);
            As[kk][c] = (c < kNO) ? A[gk * kNO + c] : 0.f;
            Bs[kk][c] = Bm[gk * kNH + n0 + c];
        }
        __syncthreads();
        #pragma unroll
        for (int kk = 0; kk < 16; kk++) {
            float4 av = *(const float4*)&As[kk][ty * 4];
            float4 bv = *(const float4*)&Bs[kk][tx * 4];
            float aa[4] = {av.x, av.y, av.z, av.w};
            float bb[4] = {bv.x, bv.y, bv.z, bv.w};
            #pragma unroll
            for (int a = 0; a < 4; a++)
                #pragma unroll
                for (int c = 0; c < 4; c++) acc[a][c] += aa[a] * bb[c];
        }
        __syncthreads();
    }
    float* Cs = Cpart + (size_t)s * kNO * kNH;
    #pragma unroll
    for (int a = 0; a < 4; a++) {
        int m = ty * 4 + a;
        if (m >= kNO) continue;
        #pragma unroll
        for (int c = 0; c < 4; c++)
            Cs[(size_t)m * kNH + n0 + tx * 4 + c] = acc[a][c];
    }
}

// ---- reductions -------------------------------------------------------------
__global__ void k_reduce_gfgr(const float* __restrict__ ws, float* __restrict__ dout) {
    int idx = blockIdx.x * 256 + threadIdx.x;  // < 620544
    const int NGF = kNH * kNI, NGR = kNH * kNH;
    float s = 0.f;
    if (idx < NGF) {
        #pragma unroll
        for (int k = 0; k < 16; k++) s += ws[O_PGF + (size_t)k * NGF + idx];
        dout[OUT_GF + idx] = s;   // LR folded into M
    } else {
        int j = idx - NGF;
        #pragma unroll
        for (int k = 0; k < 16; k++) s += ws[O_PGR + (size_t)k * NGR + j];
        dout[OUT_GR + j] = s;
    }
}

__global__ void k_reduce_go(const float* __restrict__ ws, float* __restrict__ dout) {
    int idx = blockIdx.x * 256 + threadIdx.x;  // < 10240
    const int NGO = kNO * kNH;
    float s = 0.f;
    #pragma unroll
    for (int k = 0; k < 8; k++) s += ws[O_PGO + (size_t)k * NGO + idx];
    dout[OUT_GO + idx] = LR * s;
}

extern "C" void kernel_launch(void* const* d_in, const int* in_sizes, int n_in,
                              void* d_out, int out_size, void* d_ws, size_t ws_size,
                              hipStream_t stream) {
    (void)in_sizes; (void)n_in; (void)out_size;
    const float* x     = (const float*)d_in[0];
    const float* label = (const float*)d_in[1];
    const float* w_fc1 = (const float*)d_in[3];
    const float* w_rec = (const float*)d_in[4];
    const float* w_out = (const float*)d_in[5];
    float* out = (float*)d_out;
    float* ws  = (float*)d_ws;

    if (ws_size < WS_FLOATS * sizeof(float)) return;

    // hs row 0 (= hs_{-1}) must be zero for trec scan
    hipMemsetAsync(ws + O_HS, 0, BNH * sizeof(float), stream);

    k_transpose<<<dim3(22, 16), dim3(32, 8), 0, stream>>>(w_fc1, ws + O_WT);
    k_tin<<<175, 256, 0, stream>>>(x, ws + O_TIN);
    k_xw2<<<200, 256, 0, stream>>>(x, ws + O_WT, ws + O_XW);

    k_forward<<<kB, 1024, 0, stream>>>(ws, label, w_rec, w_out, out);

    k_errscan<<<5, 256, 0, stream>>>(ws);
    k_M<<<kT * kB / 8, 256, 0, stream>>>(ws, w_out);
    k_trec<<<128, 256, 0, stream>>>(ws);

    k_gemm_tn<<<16 * 4 * 6, 256, 0, stream>>>(ws + O_M, ws + O_TIN, ws + O_PGF, kNI);
    k_gemm_tn<<<16 * 4 * 4, 256, 0, stream>>>(ws + O_M, ws + O_TREC, ws + O_PGR, kNH);
    k_gemmTN_go<<<64, 256, 0, stream>>>(ws + O_ERR, ws + O_HS + BNH, ws + O_PGO);

    k_reduce_gfgr<<<2424, 256, 0, stream>>>(ws, out);
    k_reduce_go<<<40, 256, 0, stream>>>(ws, out);
}

// Round 5
// 946.328 us; speedup vs baseline: 1.3412x; 1.0652x over previous
//
#include <hip/hip_runtime.h>
#include <hip/hip_bf16.h>

// Problem constants (B,T,NI,NH,NO fixed by the reference)
constexpr int kB  = 64;
constexpr int kT  = 100;
constexpr int kNI = 700;
constexpr int kNH = 512;
constexpr int kNO = 20;
constexpr float TAU   = 0.6f;
constexpr float TAU_O = 0.6f;
constexpr float THR   = 0.6f;
constexpr float LR    = 0.05f;

constexpr size_t BNH = (size_t)kB * kNH;   // 32768
constexpr size_t BNI = (size_t)kB * kNI;   // 44800
constexpr size_t BNO = (size_t)kB * kNO;   // 1280
constexpr int kK   = kT * kB;              // 6400 (grad-GEMM K)
constexpr int kKP  = 704;                  // padded K for xw GEMM

typedef __attribute__((ext_vector_type(8))) short short8;
typedef __attribute__((ext_vector_type(4))) float f32x4;

// ---------------- workspace layout (float offsets) ---------------------------
// Overlay region = XW[T,B,NH] + HSUR[T,B,NH] (both dead after k_M):
//   PGF (4 x [512][768] fp32), MTB (bf16 [512][6400]), TRB (bf16 [512][6400])
constexpr size_t O_XW   = 0;
constexpr size_t O_HSUR = (size_t)kT * BNH;                 // 3,276,800
constexpr size_t O_PGF  = 0;                                // 4*512*768 = 1,572,864
constexpr size_t O_MTB  = 4ull * kNH * 768;                 // 1,572,864
constexpr size_t O_TRB  = O_MTB + (size_t)kNH * kK / 2;     // 3,211,264 (ends 4,849,664 < 6,553,600)
constexpr size_t O_TIN  = 2ull * kT * BNH;                  // 6,553,600  [T,B,NI]
constexpr size_t O_HS   = O_TIN  + (size_t)kT * BNI;        // [T+1,B,NH] (row t = hs_{t-1})
constexpr size_t O_ERR  = O_HS   + (size_t)(kT + 1) * BNH;  // [T,B,NO]
constexpr size_t O_M    = O_ERR  + (size_t)kT * BNO;        // [T,B,NH]
constexpr size_t O_TREC = O_M    + (size_t)kT * BNH;        // [T,B,NH]
constexpr size_t O_WT   = O_TREC + (size_t)kT * BNH;        // [704,NH]
constexpr size_t O_PGO  = O_WT   + (size_t)kKP * kNH;       // 8 x [NO,NH]
constexpr size_t O_PGR  = O_PGO  + 8ull * kNO * kNH;        // 4 x [512][512]
constexpr size_t O_TIB  = O_PGR  + 4ull * kNH * kNH;        // bf16 [700][6400] = 2,240,000 floats
constexpr size_t WS_FLOATS = O_TIB + (size_t)kNI * kK / 2;  // 24,755,712 (~99 MB)

// d_out layout
constexpr size_t OUT_GF = (size_t)kB * kT * kNO;
constexpr size_t OUT_GR = OUT_GF + (size_t)kNH * kNI;
constexpr size_t OUT_GO = OUT_GR + (size_t)kNH * kNH;

// ---- w_fc1 [NH,NI] -> wT [704,NH], rows 700..703 zero -----------------------
__global__ void k_transpose(const float* __restrict__ w, float* __restrict__ wT) {
    __shared__ float tile[32][33];
    int i0 = blockIdx.x * 32, r0 = blockIdx.y * 32;
    int tx = threadIdx.x, ty = threadIdx.y; // 32 x 8
    #pragma unroll
    for (int k = 0; k < 32; k += 8) {
        int i = i0 + tx;
        tile[ty + k][tx] = (i < kNI) ? w[(size_t)(r0 + ty + k) * kNI + i] : 0.f;
    }
    __syncthreads();
    #pragma unroll
    for (int k = 0; k < 32; k += 8) {
        int i = i0 + ty + k;
        wT[(size_t)i * kNH + r0 + tx] = tile[tx][ty + k];
    }
}

// ---- tin[t,b,i] = TAU*tin[t-1] + x[b,t,i] ----------------------------------
__global__ __launch_bounds__(256) void k_tin(const float* __restrict__ x, float* __restrict__ tin) {
    int idx = blockIdx.x * 256 + threadIdx.x;
    int b = idx / kNI, i = idx % kNI;
    const float* xp = x + (size_t)b * kT * kNI + i;
    float v = 0.f;
    for (int t = 0; t < kT; t++) {
        v = TAU * v + xp[(size_t)t * kNI];
        tin[(size_t)t * BNI + idx] = v;
    }
}

// ---- XW = Xperm @ wT : C[m=t*64+b, n<512], K=704 (fp32, exact) --------------
__global__ __launch_bounds__(256) void k_xw2(const float* __restrict__ x,
                                             const float* __restrict__ wT,
                                             float* __restrict__ XW) {
    int bx = blockIdx.x;
    int mt = bx % 50, nt = bx / 50;
    int m0 = mt * 128, n0 = nt * 128;
    int tid = threadIdx.x, tx = tid & 15, ty = tid >> 4;
    __shared__ float As[128][20];
    __shared__ float Bs[16][128];
    float acc[8][8] = {};
    int arow = tid >> 1, ahalf = tid & 1;
    int bb = (m0 + arow) & 63, tt = (m0 + arow) >> 6;
    const float* ap = x + ((size_t)bb * kT + tt) * kNI;
    for (int k0 = 0; k0 < kKP; k0 += 16) {
        #pragma unroll
        for (int u = 0; u < 2; u++) {
            int k = k0 + ahalf * 8 + u * 4;
            float4 v = (k + 3 < kNI) ? *(const float4*)(ap + k)
                                     : make_float4(0.f, 0.f, 0.f, 0.f);
            *(float4*)&As[arow][ahalf * 8 + u * 4] = v;
        }
        #pragma unroll
        for (int u = 0; u < 2; u++) {
            int f = tid * 2 + u;
            int kk = f >> 5, c4 = f & 31;
            *(float4*)&Bs[kk][c4 * 4] =
                *(const float4*)(wT + (size_t)(k0 + kk) * kNH + n0 + c4 * 4);
        }
        __syncthreads();
        #pragma unroll
        for (int kk = 0; kk < 16; kk++) {
            float av[8];
            #pragma unroll
            for (int i = 0; i < 4; i++) {
                av[i]     = As[ty * 4 + i][kk];
                av[4 + i] = As[64 + ty * 4 + i][kk];
            }
            float4 b0 = *(const float4*)&Bs[kk][tx * 4];
            float4 b1 = *(const float4*)&Bs[kk][64 + tx * 4];
            float bvv[8] = {b0.x, b0.y, b0.z, b0.w, b1.x, b1.y, b1.z, b1.w};
            #pragma unroll
            for (int i = 0; i < 8; i++)
                #pragma unroll
                for (int j = 0; j < 8; j++) acc[i][j] += av[i] * bvv[j];
        }
        __syncthreads();
    }
    #pragma unroll
    for (int i = 0; i < 8; i++) {
        int m = m0 + ((i < 4) ? (ty * 4 + i) : (64 + ty * 4 + i - 4));
        float* dst = XW + (size_t)m * kNH + n0;
        *(float4*)(dst + tx * 4)      = make_float4(acc[i][0], acc[i][1], acc[i][2], acc[i][3]);
        *(float4*)(dst + 64 + tx * 4) = make_float4(acc[i][4], acc[i][5], acc[i][6], acc[i][7]);
    }
}

// ---- fused forward: ONE block of 1024 threads per sample --------------------
// Interleaved active list: global pos p stored at slot (p&7)*64 + (p>>3), so
// share sh reads its indices contiguously -> int4 LDS reads, 8 L2 loads
// in flight per thread.
__global__ __launch_bounds__(1024) void k_forward(float* __restrict__ ws,
                                                  const float* __restrict__ label,
                                                  const float* __restrict__ w_rec,
                                                  const float* __restrict__ w_out,
                                                  float* __restrict__ dout) {
    __shared__ float wout_ld[kNO * kNH];   // 40 KB
    __shared__ float partial[8][kNH];      // 16 KB
    __shared__ __align__(16) int list[kNH];
    __shared__ unsigned long long lmask[2][8];
    __shared__ int   cnt[8];
    __shared__ float om_ld[kNO], os_ld[kNO];

    int b = blockIdx.x, tid = threadIdx.x;
    int c4 = tid & 127, sh = tid >> 7;     // float4 column / list share
    const float4* wr4 = (const float4*)w_rec;
    for (int e = tid; e < kNO * kNH; e += 1024) wout_ld[e] = w_out[e];
    if (tid < kNO) { om_ld[tid] = 0.f; os_ld[tid] = 0.f; }
    float hm = 0.f, sp_prev = 0.f;
    int nact = 0;
    __syncthreads();

    for (int t = 0; t < kT; t++) {
        // ---- A: gather active rows of w_rec (list from step t-1) ----
        float xw = 0.f;
        if (tid < kNH) xw = ws[O_XW + ((size_t)t * 64 + b) * kNH + tid];
        float4 a0 = make_float4(0.f, 0.f, 0.f, 0.f), a1 = a0, a2 = a0, a3 = a0;
        int n_u = (nact > sh) ? ((nact - sh + 7) >> 3) : 0;
        const int base = sh * 64;
        int u = 0;
        for (; u + 8 <= n_u; u += 8) {
            int4 i0 = *(const int4*)&list[base + u];
            int4 i1 = *(const int4*)&list[base + u + 4];
            float4 v0 = wr4[(size_t)i0.x * 128 + c4];
            float4 v1 = wr4[(size_t)i0.y * 128 + c4];
            float4 v2 = wr4[(size_t)i0.z * 128 + c4];
            float4 v3 = wr4[(size_t)i0.w * 128 + c4];
            float4 v4 = wr4[(size_t)i1.x * 128 + c4];
            float4 v5 = wr4[(size_t)i1.y * 128 + c4];
            float4 v6 = wr4[(size_t)i1.z * 128 + c4];
            float4 v7 = wr4[(size_t)i1.w * 128 + c4];
            a0.x += v0.x; a0.y += v0.y; a0.z += v0.z; a0.w += v0.w;
            a1.x += v1.x; a1.y += v1.y; a1.z += v1.z; a1.w += v1.w;
            a2.x += v2.x; a2.y += v2.y; a2.z += v2.z; a2.w += v2.w;
            a3.x += v3.x; a3.y += v3.y; a3.z += v3.z; a3.w += v3.w;
            a0.x += v4.x; a0.y += v4.y; a0.z += v4.z; a0.w += v4.w;
            a1.x += v5.x; a1.y += v5.y; a1.z += v5.z; a1.w += v5.w;
            a2.x += v6.x; a2.y += v6.y; a2.z += v6.z; a2.w += v6.w;
            a3.x += v7.x; a3.y += v7.y; a3.z += v7.z; a3.w += v7.w;
        }
        for (; u < n_u; u++) {
            float4 v = wr4[(size_t)list[base + u] * 128 + c4];
            a0.x += v.x; a0.y += v.y; a0.z += v.z; a0.w += v.w;
        }
        a0.x += a1.x + a2.x + a3.x; a0.y += a1.y + a2.y + a3.y;
        a0.z += a1.z + a2.z + a3.z; a0.w += a1.w + a2.w + a3.w;
        *(float4*)&partial[sh][c4 * 4] = a0;
        __syncthreads();
        // ---- B: LIF update (threads < 512) ----
        if (tid < kNH) {
            float rec = ((partial[0][tid] + partial[1][tid]) + (partial[2][tid] + partial[3][tid]))
                      + ((partial[4][tid] + partial[5][tid]) + (partial[6][tid] + partial[7][tid]));
            hm = TAU * hm * (1.f - sp_prev) + (xw + rec);
            bool v = (hm >= THR);
            float sp = v ? 1.f : 0.f;
            sp_prev = sp;
            ws[O_HS + (size_t)(t + 1) * BNH + (size_t)b * kNH + tid] = sp;
            ws[O_HSUR + (size_t)t * BNH + (size_t)b * kNH + tid] =
                TAU * fmaxf(0.f, 1.f - fabsf(hm - THR) * (1.f / THR));
            unsigned long long bal = __ballot(v);
            if ((tid & 63) == 0) {
                int w = tid >> 6;
                lmask[t & 1][w] = bal;
                cnt[w] = __popcll(bal);
            }
        }
        __syncthreads();
        // ---- C: interleaved list build (tid<512) || output layer (waves 8..12)
        int bases[8], tot = 0;
        #pragma unroll
        for (int k = 0; k < 8; k++) { bases[k] = tot; tot += cnt[k]; }
        nact = tot;
        if (tid < kNH) {
            unsigned long long m = lmask[t & 1][tid >> 6];
            int bit = tid & 63;
            if ((m >> bit) & 1) {
                int p = bases[tid >> 6] + __popcll(m & (((unsigned long long)1 << bit) - 1ull));
                list[(p & 7) * 64 + (p >> 3)] = tid;
            }
        } else {
            int uu = tid - kNH, lane = uu & 63, q = uu >> 6;
            if (q < 5) {
                #pragma unroll
                for (int r = 0; r < 4; r++) {
                    int o = q * 4 + r;
                    float p = 0.f;
                    #pragma unroll
                    for (int k = 0; k < 8; k++)
                        if ((lmask[t & 1][k] >> lane) & 1) p += wout_ld[o * kNH + 64 * k + lane];
                    #pragma unroll
                    for (int off = 32; off >= 1; off >>= 1) p += __shfl_xor(p, off);
                    if (lane == 0) {
                        float om = om_ld[o], os = os_ld[o];
                        float om_n = TAU * om * (1.f - os) + p;
                        float os_n = (om_n >= THR) ? 1.f : 0.f;
                        om_ld[o] = om_n; os_ld[o] = os_n;
                        ws[O_ERR + (size_t)t * BNO + (size_t)b * kNO + o] =
                            os_n - label[((size_t)b * kT + t) * kNO + o];
                        dout[((size_t)b * kT + t) * kNO + o] = os_n;
                    }
                }
            }
        }
        __syncthreads();
    }
}

// ---- reverse kappa filter of err (in place) --------------------------------
__global__ void k_errscan(float* __restrict__ ws) {
    int idx = blockIdx.x * 256 + threadIdx.x;  // < 1280
    float v = 0.f;
    for (int t = kT - 1; t >= 0; t--) {
        float* p = ws + O_ERR + (size_t)t * BNO + idx;
        v = *p + TAU_O * v;
        *p = v;
    }
}

// ---- M[tb,r] = LR * (errf[tb,:] @ w_out)[r] * hsur[tb,r] --------------------
__global__ __launch_bounds__(256) void k_M(float* __restrict__ ws, const float* __restrict__ w_out) {
    __shared__ float wo[kNO * kNH];
    __shared__ float ef[8 * kNO];
    int tid = threadIdx.x;
    int tb0 = blockIdx.x * 8;
    for (int e = tid; e < kNO * kNH; e += 256) wo[e] = w_out[e];
    for (int e = tid; e < 8 * kNO; e += 256) ef[e] = ws[O_ERR + (size_t)tb0 * kNO + e];
    __syncthreads();
    for (int e = tid; e < 8 * kNH; e += 256) {
        int tbl = e >> 9, r = e & 511;
        float s = 0.f;
        #pragma unroll
        for (int o = 0; o < kNO; o++) s += ef[tbl * kNO + o] * wo[o * kNH + r];
        size_t g = (size_t)(tb0 + tbl) * kNH + r;
        ws[O_M + g] = LR * s * ws[O_HSUR + g];
    }
}

// ---- trec[t,b,j] = TAU*trec[t-1] + hs_{t-1} --------------------------------
__global__ void k_trec(float* __restrict__ ws) {
    size_t idx = (size_t)blockIdx.x * 256 + threadIdx.x;  // < BNH
    float v = 0.f;
    for (int t = 0; t < kT; t++) {
        v = TAU * v + ws[O_HS + (size_t)t * BNH + idx];
        ws[O_TREC + (size_t)t * BNH + idx] = v;
    }
}

// ---- transposed bf16 cast: dst[n][k=6400] = bf16(src[k][n]) -----------------
__global__ void k_castT(const float* __restrict__ src, __hip_bfloat16* __restrict__ dst, int N) {
    __shared__ float tile[32][33];
    int k0 = blockIdx.x * 32, n0 = blockIdx.y * 32;
    int tx = threadIdx.x, ty = threadIdx.y;  // 32 x 8
    #pragma unroll
    for (int j = 0; j < 32; j += 8) {
        int n = n0 + tx;
        tile[ty + j][tx] = (n < N) ? src[(size_t)(k0 + ty + j) * N + n] : 0.f;
    }
    __syncthreads();
    #pragma unroll
    for (int j = 0; j < 32; j += 8) {
        int n = n0 + ty + j;
        if (n < N) dst[(size_t)n * kK + k0 + tx] = __float2bfloat16(tile[tx][ty + j]);
    }
}

// ---- bf16 MFMA NT GEMM: C[m,n] = sum_k A[m][k]*B[n][k], K=6400, splitK=4 ----
// A [512][6400] bf16, B [Nrows][6400] bf16. 128x128 tile, 4 waves 2x2,
// each wave 64x64 via 4x4 mfma_f32_16x16x32_bf16 tiles. Cpart fp32 [s][512][ldc].
__global__ __launch_bounds__(256) void k_gemm_nt(const unsigned short* __restrict__ A,
                                                 const unsigned short* __restrict__ B,
                                                 float* __restrict__ Cpart,
                                                 int Nrows, int ldc) {
    constexpr int KC = kK / 4, BK = 64, LDT = 72;  // LDT*2B=144 (16B-mult)
    int bx = blockIdx.x;
    int s = bx & 3, mt = (bx >> 2) & 3, nt = bx >> 4;
    int m0 = mt * 128, n0 = nt * 128, k0 = s * KC;
    int tid = threadIdx.x;
    int wave = tid >> 6, lane = tid & 63;
    int wm = wave & 1, wn = wave >> 1;
    __shared__ unsigned short As[128 * LDT];
    __shared__ unsigned short Bs[128 * LDT];
    f32x4 acc[4][4];
    #pragma unroll
    for (int i = 0; i < 4; i++)
        #pragma unroll
        for (int j = 0; j < 4; j++) acc[i][j] = (f32x4){0.f, 0.f, 0.f, 0.f};

    for (int kb = 0; kb < KC; kb += BK) {
        int kg = k0 + kb;
        #pragma unroll
        for (int p = 0; p < 4; p++) {
            int f = tid + p * 256;
            int row = f >> 3, seg = f & 7;
            *(short8*)&As[row * LDT + seg * 8] =
                *(const short8*)&A[(size_t)(m0 + row) * kK + kg + seg * 8];
            short8 bv = {};
            if (n0 + row < Nrows)
                bv = *(const short8*)&B[(size_t)(n0 + row) * kK + kg + seg * 8];
            *(short8*)&Bs[row * LDT + seg * 8] = bv;
        }
        __syncthreads();
        #pragma unroll
        for (int h = 0; h < 2; h++) {
            int kof = h * 32 + (lane >> 4) * 8;
            short8 af[4], bf[4];
            #pragma unroll
            for (int i = 0; i < 4; i++)
                af[i] = *(short8*)&As[(wm * 64 + i * 16 + (lane & 15)) * LDT + kof];
            #pragma unroll
            for (int j = 0; j < 4; j++)
                bf[j] = *(short8*)&Bs[(wn * 64 + j * 16 + (lane & 15)) * LDT + kof];
            #pragma unroll
            for (int i = 0; i < 4; i++)
                #pragma unroll
                for (int j = 0; j < 4; j++)
                    acc[i][j] = __builtin_amdgcn_mfma_f32_16x16x32_bf16(af[i], bf[j], acc[i][j], 0, 0, 0);
        }
        __syncthreads();
    }
    // epilogue: D mapping col(n)=lane&15, row(m)=(lane>>4)*4+reg
    float* C = Cpart + (size_t)s * kNH * ldc;
    int rbase = (lane >> 4) * 4, col = lane & 15;
    #pragma unroll
    for (int i = 0; i < 4; i++)
        #pragma unroll
        for (int j = 0; j < 4; j++) {
            int n = n0 + wn * 64 + j * 16 + col;
            #pragma unroll
            for (int r = 0; r < 4; r++) {
                int m = m0 + wm * 64 + i * 16 + rbase + r;
                C[(size_t)m * ldc + n] = acc[i][j][r];
            }
        }
}

// ---- small TN GEMM for go (M=20), fp32 -------------------------------------
__global__ __launch_bounds__(256) void k_gemmTN_go(const float* __restrict__ A,
                                                   const float* __restrict__ Bm,
                                                   float* __restrict__ Cpart) {
    int bx = blockIdx.x, tid = threadIdx.x;  // grid 64 = 8 s * 8 nt
    int s = bx & 7, nt = bx >> 3;
    int n0 = nt * 64, k0 = s * 800;
    __shared__ float As[16][64];
    __shared__ float Bs[16][64];
    int tx = tid & 15, ty = tid >> 4;
    float acc[4][4] = {};
    for (int kb = 0; kb < 800; kb += 16) {
        #pragma unroll
        for (int e = tid; e < 1024; e += 256) {
            int kk = e >> 6, c = e & 63;
            size_t gk = (size_t)(k0 + kb + kk);
            As[kk][c] = (c < kNO) ? A[gk * kNO + c] : 0.f;
            Bs[kk][c] = Bm[gk * kNH + n0 + c];
        }
        __syncthreads();
        #pragma unroll
        for (int kk = 0; kk < 16; kk++) {
            float4 av = *(const float4*)&As[kk][ty * 4];
            float4 bv = *(const float4*)&Bs[kk][tx * 4];
            float aa[4] = {av.x, av.y, av.z, av.w};
            float bb[4] = {bv.x, bv.y, bv.z, bv.w};
            #pragma unroll
            for (int a = 0; a < 4; a++)
                #pragma unroll
                for (int c = 0; c < 4; c++) acc[a][c] += aa[a] * bb[c];
        }
        __syncthreads();
    }
    float* Cs = Cpart + (size_t)s * kNO * kNH;
    #pragma unroll
    for (int a = 0; a < 4; a++) {
        int m = ty * 4 + a;
        if (m >= kNO) continue;
        #pragma unroll
        for (int c = 0; c < 4; c++)
            Cs[(size_t)m * kNH + n0 + tx * 4 + c] = acc[a][c];
    }
}

// ---- reductions -------------------------------------------------------------
__global__ void k_reduce_gfgr(const float* __restrict__ ws, float* __restrict__ dout) {
    int idx = blockIdx.x * 256 + threadIdx.x;  // < 620544
    const int NGF = kNH * kNI, NGR = kNH * kNH;
    float s = 0.f;
    if (idx < NGF) {
        int m = idx / kNI, n = idx - m * kNI;
        size_t src = O_PGF + (size_t)m * 768 + n;
        #pragma unroll
        for (int k = 0; k < 4; k++) s += ws[src + (size_t)k * kNH * 768];
        dout[OUT_GF + idx] = s;   // LR folded into M
    } else if (idx < NGF + NGR) {
        int j = idx - NGF;
        #pragma unroll
        for (int k = 0; k < 4; k++) s += ws[O_PGR + j + (size_t)k * NGR];
        dout[OUT_GR + j] = s;
    }
}

__global__ void k_reduce_go(const float* __restrict__ ws, float* __restrict__ dout) {
    int idx = blockIdx.x * 256 + threadIdx.x;  // < 10240
    const int NGO = kNO * kNH;
    float s = 0.f;
    #pragma unroll
    for (int k = 0; k < 8; k++) s += ws[O_PGO + (size_t)k * NGO + idx];
    dout[OUT_GO + idx] = LR * s;
}

extern "C" void kernel_launch(void* const* d_in, const int* in_sizes, int n_in,
                              void* d_out, int out_size, void* d_ws, size_t ws_size,
                              hipStream_t stream) {
    (void)in_sizes; (void)n_in; (void)out_size;
    const float* x     = (const float*)d_in[0];
    const float* label = (const float*)d_in[1];
    const float* w_fc1 = (const float*)d_in[3];
    const float* w_rec = (const float*)d_in[4];
    const float* w_out = (const float*)d_in[5];
    float* out = (float*)d_out;
    float* ws  = (float*)d_ws;

    if (ws_size < WS_FLOATS * sizeof(float)) return;

    __hip_bfloat16* mtb = (__hip_bfloat16*)(ws + O_MTB);
    __hip_bfloat16* trb = (__hip_bfloat16*)(ws + O_TRB);
    __hip_bfloat16* tib = (__hip_bfloat16*)(ws + O_TIB);

    // hs row 0 (= hs_{-1}) must be zero for trec scan
    hipMemsetAsync(ws + O_HS, 0, BNH * sizeof(float), stream);

    k_transpose<<<dim3(22, 16), dim3(32, 8), 0, stream>>>(w_fc1, ws + O_WT);
    k_tin<<<175, 256, 0, stream>>>(x, ws + O_TIN);
    k_xw2<<<200, 256, 0, stream>>>(x, ws + O_WT, ws + O_XW);

    k_forward<<<kB, 1024, 0, stream>>>(ws, label, w_rec, w_out, out);

    k_errscan<<<5, 256, 0, stream>>>(ws);
    k_M<<<kT * kB / 8, 256, 0, stream>>>(ws, w_out);
    k_trec<<<128, 256, 0, stream>>>(ws);

    // bf16 transposed-cast producers for the MFMA grad GEMMs
    k_castT<<<dim3(200, 16), dim3(32, 8), 0, stream>>>(ws + O_M,    mtb, kNH);
    k_castT<<<dim3(200, 22), dim3(32, 8), 0, stream>>>(ws + O_TIN,  tib, kNI);
    k_castT<<<dim3(200, 16), dim3(32, 8), 0, stream>>>(ws + O_TREC, trb, kNH);

    // gf: [512,700] = Mt x tint  (96 blocks = 4 splitK * 4 mt * 6 nt)
    k_gemm_nt<<<96, 256, 0, stream>>>((const unsigned short*)mtb, (const unsigned short*)tib,
                                      ws + O_PGF, kNI, 768);
    // gr: [512,512] = Mt x trect (64 blocks)
    k_gemm_nt<<<64, 256, 0, stream>>>((const unsigned short*)mtb, (const unsigned short*)trb,
                                      ws + O_PGR, kNH, kNH);
    // go: fp32 small GEMM
    k_gemmTN_go<<<64, 256, 0, stream>>>(ws + O_ERR, ws + O_HS + BNH, ws + O_PGO);

    k_reduce_gfgr<<<2424, 256, 0, stream>>>(ws, out);
    k_reduce_go<<<40, 256, 0, stream>>>(ws, out);
}

// Round 6
// 777.870 us; speedup vs baseline: 1.6316x; 1.2166x over previous
//
#include <hip/hip_runtime.h>
#include <hip/hip_bf16.h>

// Problem constants (B,T,NI,NH,NO fixed by the reference)
constexpr int kB  = 64;
constexpr int kT  = 100;
constexpr int kNI = 700;
constexpr int kNH = 512;
constexpr int kNO = 20;
constexpr float TAU   = 0.6f;
constexpr float TAU_O = 0.6f;
constexpr float THR   = 0.6f;
constexpr float LR    = 0.05f;

constexpr size_t BNH = (size_t)kB * kNH;   // 32768
constexpr size_t BNI = (size_t)kB * kNI;   // 44800
constexpr size_t BNO = (size_t)kB * kNO;   // 1280
constexpr int kK   = kT * kB;              // 6400 (grad-GEMM K)
constexpr int kKP  = 704;                  // padded K for xw GEMM

typedef __attribute__((ext_vector_type(8))) short short8;
typedef __attribute__((ext_vector_type(4))) float f32x4;

// ---------------- workspace layout (float offsets) ---------------------------
constexpr size_t O_XW   = 0;
constexpr size_t O_HSUR = (size_t)kT * BNH;                 // 3,276,800
constexpr size_t O_PGF  = 0;                                // overlay: 4 x [512][768]
constexpr size_t O_MTB  = 4ull * kNH * 768;                 // bf16 [512][6400]
constexpr size_t O_TRB  = O_MTB + (size_t)kNH * kK / 2;     // bf16 [512][6400]
constexpr size_t O_TIN  = 2ull * kT * BNH;                  // [T,B,NI]
constexpr size_t O_HS   = O_TIN  + (size_t)kT * BNI;        // [T+1,B,NH] (row t = hs_{t-1})
constexpr size_t O_ERR  = O_HS   + (size_t)(kT + 1) * BNH;  // [T,B,NO]
constexpr size_t O_M    = O_ERR  + (size_t)kT * BNO;        // [T,B,NH]
constexpr size_t O_TREC = O_M    + (size_t)kT * BNH;        // [T,B,NH]
constexpr size_t O_WT   = O_TREC + (size_t)kT * BNH;        // [704,NH]
constexpr size_t O_PGO  = O_WT   + (size_t)kKP * kNH;       // 8 x [NO,NH]
constexpr size_t O_PGR  = O_PGO  + 8ull * kNO * kNH;        // 4 x [512][512]
constexpr size_t O_TIB  = O_PGR  + 4ull * kNH * kNH;        // bf16 [700][6400]
constexpr size_t O_MSK  = O_TIB  + (size_t)kNI * kK / 2;    // u64 [T][B][8] = 102,400 floats
constexpr size_t WS_FLOATS = O_MSK + 102400;                // ~99.4 MB

// d_out layout
constexpr size_t OUT_GF = (size_t)kB * kT * kNO;
constexpr size_t OUT_GR = OUT_GF + (size_t)kNH * kNI;
constexpr size_t OUT_GO = OUT_GR + (size_t)kNH * kNH;

// ---- w_fc1 [NH,NI] -> wT [704,NH], rows 700..703 zero -----------------------
__global__ void k_transpose(const float* __restrict__ w, float* __restrict__ wT) {
    __shared__ float tile[32][33];
    int i0 = blockIdx.x * 32, r0 = blockIdx.y * 32;
    int tx = threadIdx.x, ty = threadIdx.y; // 32 x 8
    #pragma unroll
    for (int k = 0; k < 32; k += 8) {
        int i = i0 + tx;
        tile[ty + k][tx] = (i < kNI) ? w[(size_t)(r0 + ty + k) * kNI + i] : 0.f;
    }
    __syncthreads();
    #pragma unroll
    for (int k = 0; k < 32; k += 8) {
        int i = i0 + ty + k;
        wT[(size_t)i * kNH + r0 + tx] = tile[tx][ty + k];
    }
}

// ---- tin[t,b,i] = TAU*tin[t-1] + x[b,t,i] ----------------------------------
__global__ __launch_bounds__(256) void k_tin(const float* __restrict__ x, float* __restrict__ tin) {
    int idx = blockIdx.x * 256 + threadIdx.x;
    int b = idx / kNI, i = idx % kNI;
    const float* xp = x + (size_t)b * kT * kNI + i;
    float v = 0.f;
    for (int t = 0; t < kT; t++) {
        v = TAU * v + xp[(size_t)t * kNI];
        tin[(size_t)t * BNI + idx] = v;
    }
}

// ---- XW = Xperm @ wT : C[m=t*64+b, n<512], K=704 (fp32, exact) --------------
__global__ __launch_bounds__(256) void k_xw2(const float* __restrict__ x,
                                             const float* __restrict__ wT,
                                             float* __restrict__ XW) {
    int bx = blockIdx.x;
    int mt = bx % 50, nt = bx / 50;
    int m0 = mt * 128, n0 = nt * 128;
    int tid = threadIdx.x, tx = tid & 15, ty = tid >> 4;
    __shared__ float As[128][20];
    __shared__ float Bs[16][128];
    float acc[8][8] = {};
    int arow = tid >> 1, ahalf = tid & 1;
    int bb = (m0 + arow) & 63, tt = (m0 + arow) >> 6;
    const float* ap = x + ((size_t)bb * kT + tt) * kNI;
    for (int k0 = 0; k0 < kKP; k0 += 16) {
        #pragma unroll
        for (int u = 0; u < 2; u++) {
            int k = k0 + ahalf * 8 + u * 4;
            float4 v = (k + 3 < kNI) ? *(const float4*)(ap + k)
                                     : make_float4(0.f, 0.f, 0.f, 0.f);
            *(float4*)&As[arow][ahalf * 8 + u * 4] = v;
        }
        #pragma unroll
        for (int u = 0; u < 2; u++) {
            int f = tid * 2 + u;
            int kk = f >> 5, c4 = f & 31;
            *(float4*)&Bs[kk][c4 * 4] =
                *(const float4*)(wT + (size_t)(k0 + kk) * kNH + n0 + c4 * 4);
        }
        __syncthreads();
        #pragma unroll
        for (int kk = 0; kk < 16; kk++) {
            float av[8];
            #pragma unroll
            for (int i = 0; i < 4; i++) {
                av[i]     = As[ty * 4 + i][kk];
                av[4 + i] = As[64 + ty * 4 + i][kk];
            }
            float4 b0 = *(const float4*)&Bs[kk][tx * 4];
            float4 b1 = *(const float4*)&Bs[kk][64 + tx * 4];
            float bvv[8] = {b0.x, b0.y, b0.z, b0.w, b1.x, b1.y, b1.z, b1.w};
            #pragma unroll
            for (int i = 0; i < 8; i++)
                #pragma unroll
                for (int j = 0; j < 8; j++) acc[i][j] += av[i] * bvv[j];
        }
        __syncthreads();
    }
    #pragma unroll
    for (int i = 0; i < 8; i++) {
        int m = m0 + ((i < 4) ? (ty * 4 + i) : (64 + ty * 4 + i - 4));
        float* dst = XW + (size_t)m * kNH + n0;
        *(float4*)(dst + tx * 4)      = make_float4(acc[i][0], acc[i][1], acc[i][2], acc[i][3]);
        *(float4*)(dst + 64 + tx * 4) = make_float4(acc[i][4], acc[i][5], acc[i][6], acc[i][7]);
    }
}

// ---- fused forward: ONE block of 832 threads (13 waves) per sample ----------
// Waves 0-7: gather. Wave w owns j-window [64w,64w+64); walks its own spike
// mask in a register (ctz loop) -> only ONE broadcast ds_read_b64 dependency.
// Waves 8-12: output LIF layer for step t-1 (reads LDS mask history).
// 2 barriers/step. Spikes exit as u64 masks (64 B/step); hs/trec densified
// post-hoc by k_hs_trec.
__global__ __launch_bounds__(832) void k_forward(float* __restrict__ ws,
                                                 const float* __restrict__ label,
                                                 const float* __restrict__ w_rec,
                                                 const float* __restrict__ w_out,
                                                 float* __restrict__ dout,
                                                 unsigned long long* __restrict__ gmask) {
    __shared__ float wout_ld[kNO * kNH];          // 40 KB
    __shared__ float partial[8][kNH];             // 16 KB
    __shared__ unsigned long long mh[kT * 8];     // 6.4 KB mask history

    int b = blockIdx.x, tid = threadIdx.x;
    int wave = tid >> 6, lane = tid & 63;
    const float4* wr4 = (const float4*)w_rec;
    for (int e = tid; e < kNO * kNH; e += 832) wout_ld[e] = w_out[e];
    float hm = 0.f, sp_prev = 0.f;
    float om_r[4] = {0.f, 0.f, 0.f, 0.f}, os_r[4] = {0.f, 0.f, 0.f, 0.f};
    int q = wave - 8;
    __syncthreads();

    for (int t = 0; t < kT; t++) {
        float xw = 0.f;
        if (wave < 8) {
            // ---- A: gather own window's active w_rec rows ----
            xw = ws[O_XW + ((size_t)t * 64 + b) * kNH + tid];
            unsigned long long m = (t > 0) ? mh[(t - 1) * 8 + wave] : 0ull;
            float4 aa = make_float4(0.f, 0.f, 0.f, 0.f), ab = aa;
            const int coff = lane * 2;
            while (m) {
                int j = __builtin_ctzll(m); m &= (m - 1);
                const float4* row = wr4 + ((size_t)(wave * 64 + j) * 128);
                float4 va = row[coff], vb = row[coff + 1];
                aa.x += va.x; aa.y += va.y; aa.z += va.z; aa.w += va.w;
                ab.x += vb.x; ab.y += vb.y; ab.z += vb.z; ab.w += vb.w;
            }
            *(float4*)&partial[wave][lane * 8]     = aa;
            *(float4*)&partial[wave][lane * 8 + 4] = ab;
        } else if (t > 0) {
            // ---- output LIF layer for step t-1 (wave q = 0..4) ----
            int to = t - 1;
            unsigned long long mk[8];
            #pragma unroll
            for (int k = 0; k < 8; k++) mk[k] = mh[to * 8 + k];
            #pragma unroll
            for (int r = 0; r < 4; r++) {
                int o = q * 4 + r;
                float p = 0.f;
                #pragma unroll
                for (int k = 0; k < 8; k++)
                    if ((mk[k] >> lane) & 1) p += wout_ld[o * kNH + 64 * k + lane];
                #pragma unroll
                for (int off = 32; off >= 1; off >>= 1) p += __shfl_xor(p, off);
                if (lane == 0) {
                    float om_n = TAU * om_r[r] * (1.f - os_r[r]) + p;
                    float os_n = (om_n >= THR) ? 1.f : 0.f;
                    om_r[r] = om_n; os_r[r] = os_n;
                    ws[O_ERR + (size_t)to * BNO + (size_t)b * kNO + o] =
                        os_n - label[((size_t)b * kT + to) * kNO + o];
                    dout[((size_t)b * kT + to) * kNO + o] = os_n;
                }
            }
        }
        __syncthreads();
        // ---- B: LIF update (threads < 512) ----
        if (tid < kNH) {
            float rec = ((partial[0][tid] + partial[1][tid]) + (partial[2][tid] + partial[3][tid]))
                      + ((partial[4][tid] + partial[5][tid]) + (partial[6][tid] + partial[7][tid]));
            hm = TAU * hm * (1.f - sp_prev) + (xw + rec);
            bool v = (hm >= THR);
            float sp = v ? 1.f : 0.f;
            sp_prev = sp;
            ws[O_HSUR + (size_t)t * BNH + (size_t)b * kNH + tid] =
                TAU * fmaxf(0.f, 1.f - fabsf(hm - THR) * (1.f / THR));
            unsigned long long bal = __ballot(v);
            if (lane == 0) {
                mh[t * 8 + wave] = bal;
                gmask[((size_t)t * 64 + b) * 8 + wave] = bal;
            }
        }
        __syncthreads();
    }
    // tail: output layer for t = 99
    if (wave >= 8) {
        int to = kT - 1;
        unsigned long long mk[8];
        #pragma unroll
        for (int k = 0; k < 8; k++) mk[k] = mh[to * 8 + k];
        #pragma unroll
        for (int r = 0; r < 4; r++) {
            int o = q * 4 + r;
            float p = 0.f;
            #pragma unroll
            for (int k = 0; k < 8; k++)
                if ((mk[k] >> lane) & 1) p += wout_ld[o * kNH + 64 * k + lane];
            #pragma unroll
            for (int off = 32; off >= 1; off >>= 1) p += __shfl_xor(p, off);
            if (lane == 0) {
                float om_n = TAU * om_r[r] * (1.f - os_r[r]) + p;
                float os_n = (om_n >= THR) ? 1.f : 0.f;
                ws[O_ERR + (size_t)to * BNO + (size_t)b * kNO + o] =
                    os_n - label[((size_t)b * kT + to) * kNO + o];
                dout[((size_t)b * kT + to) * kNO + o] = os_n;
            }
        }
    }
}

// ---- densify spikes: hs[t+1] = spike(t); trec[t] = TAU*trec[t-1]+spike(t-1) -
__global__ __launch_bounds__(256) void k_hs_trec(float* __restrict__ ws,
                                                 const unsigned long long* __restrict__ gmask) {
    size_t idx = (size_t)blockIdx.x * 256 + threadIdx.x;  // < BNH
    int b = (int)(idx >> 9), n = (int)(idx & 511);
    int w = n >> 6, bit = n & 63;
    float v = 0.f, prev = 0.f;
    for (int t = 0; t < kT; t++) {
        v = TAU * v + prev;
        ws[O_TREC + (size_t)t * BNH + idx] = v;
        float cur = (float)((gmask[((size_t)t * 64 + b) * 8 + w] >> bit) & 1ull);
        ws[O_HS + (size_t)(t + 1) * BNH + idx] = cur;
        prev = cur;
    }
}

// ---- reverse kappa filter of err (in place) --------------------------------
__global__ void k_errscan(float* __restrict__ ws) {
    int idx = blockIdx.x * 256 + threadIdx.x;  // < 1280
    float v = 0.f;
    for (int t = kT - 1; t >= 0; t--) {
        float* p = ws + O_ERR + (size_t)t * BNO + idx;
        v = *p + TAU_O * v;
        *p = v;
    }
}

// ---- M[tb,r] = LR * (errf[tb,:] @ w_out)[r] * hsur[tb,r] --------------------
__global__ __launch_bounds__(256) void k_M(float* __restrict__ ws, const float* __restrict__ w_out) {
    __shared__ float wo[kNO * kNH];
    __shared__ float ef[8 * kNO];
    int tid = threadIdx.x;
    int tb0 = blockIdx.x * 8;
    for (int e = tid; e < kNO * kNH; e += 256) wo[e] = w_out[e];
    for (int e = tid; e < 8 * kNO; e += 256) ef[e] = ws[O_ERR + (size_t)tb0 * kNO + e];
    __syncthreads();
    for (int e = tid; e < 8 * kNH; e += 256) {
        int tbl = e >> 9, r = e & 511;
        float s = 0.f;
        #pragma unroll
        for (int o = 0; o < kNO; o++) s += ef[tbl * kNO + o] * wo[o * kNH + r];
        size_t g = (size_t)(tb0 + tbl) * kNH + r;
        ws[O_M + g] = LR * s * ws[O_HSUR + g];
    }
}

// ---- transposed bf16 cast: dst[n][k=6400] = bf16(src[k][n]) -----------------
__global__ void k_castT(const float* __restrict__ src, __hip_bfloat16* __restrict__ dst, int N) {
    __shared__ float tile[32][33];
    int k0 = blockIdx.x * 32, n0 = blockIdx.y * 32;
    int tx = threadIdx.x, ty = threadIdx.y;  // 32 x 8
    #pragma unroll
    for (int j = 0; j < 32; j += 8) {
        int n = n0 + tx;
        tile[ty + j][tx] = (n < N) ? src[(size_t)(k0 + ty + j) * N + n] : 0.f;
    }
    __syncthreads();
    #pragma unroll
    for (int j = 0; j < 32; j += 8) {
        int n = n0 + ty + j;
        if (n < N) dst[(size_t)n * kK + k0 + tx] = __float2bfloat16(tile[tx][ty + j]);
    }
}

// ---- bf16 MFMA NT GEMM: C[m,n] = sum_k A[m][k]*B[n][k], K=6400, splitK=4 ----
__global__ __launch_bounds__(256) void k_gemm_nt(const unsigned short* __restrict__ A,
                                                 const unsigned short* __restrict__ B,
                                                 float* __restrict__ Cpart,
                                                 int Nrows, int ldc) {
    constexpr int KC = kK / 4, BK = 64, LDT = 72;
    int bx = blockIdx.x;
    int s = bx & 3, mt = (bx >> 2) & 3, nt = bx >> 4;
    int m0 = mt * 128, n0 = nt * 128, k0 = s * KC;
    int tid = threadIdx.x;
    int wave = tid >> 6, lane = tid & 63;
    int wm = wave & 1, wn = wave >> 1;
    __shared__ unsigned short As[128 * LDT];
    __shared__ unsigned short Bs[128 * LDT];
    f32x4 acc[4][4];
    #pragma unroll
    for (int i = 0; i < 4; i++)
        #pragma unroll
        for (int j = 0; j < 4; j++) acc[i][j] = (f32x4){0.f, 0.f, 0.f, 0.f};

    for (int kb = 0; kb < KC; kb += BK) {
        int kg = k0 + kb;
        #pragma unroll
        for (int p = 0; p < 4; p++) {
            int f = tid + p * 256;
            int row = f >> 3, seg = f & 7;
            *(short8*)&As[row * LDT + seg * 8] =
                *(const short8*)&A[(size_t)(m0 + row) * kK + kg + seg * 8];
            short8 bv = {};
            if (n0 + row < Nrows)
                bv = *(const short8*)&B[(size_t)(n0 + row) * kK + kg + seg * 8];
            *(short8*)&Bs[row * LDT + seg * 8] = bv;
        }
        __syncthreads();
        #pragma unroll
        for (int h = 0; h < 2; h++) {
            int kof = h * 32 + (lane >> 4) * 8;
            short8 af[4], bf[4];
            #pragma unroll
            for (int i = 0; i < 4; i++)
                af[i] = *(short8*)&As[(wm * 64 + i * 16 + (lane & 15)) * LDT + kof];
            #pragma unroll
            for (int j = 0; j < 4; j++)
                bf[j] = *(short8*)&Bs[(wn * 64 + j * 16 + (lane & 15)) * LDT + kof];
            #pragma unroll
            for (int i = 0; i < 4; i++)
                #pragma unroll
                for (int j = 0; j < 4; j++)
                    acc[i][j] = __builtin_amdgcn_mfma_f32_16x16x32_bf16(af[i], bf[j], acc[i][j], 0, 0, 0);
        }
        __syncthreads();
    }
    float* C = Cpart + (size_t)s * kNH * ldc;
    int rbase = (lane >> 4) * 4, col = lane & 15;
    #pragma unroll
    for (int i = 0; i < 4; i++)
        #pragma unroll
        for (int j = 0; j < 4; j++) {
            int n = n0 + wn * 64 + j * 16 + col;
            #pragma unroll
            for (int r = 0; r < 4; r++) {
                int m = m0 + wm * 64 + i * 16 + rbase + r;
                C[(size_t)m * ldc + n] = acc[i][j][r];
            }
        }
}

// ---- small TN GEMM for go (M=20), fp32 -------------------------------------
__global__ __launch_bounds__(256) void k_gemmTN_go(const float* __restrict__ A,
                                                   const float* __restrict__ Bm,
                                                   float* __restrict__ Cpart) {
    int bx = blockIdx.x, tid = threadIdx.x;  // grid 64 = 8 s * 8 nt
    int s = bx & 7, nt = bx >> 3;
    int n0 = nt * 64, k0 = s * 800;
    __shared__ float As[16][64];
    __shared__ float Bs[16][64];
    int tx = tid & 15, ty = tid >> 4;
    float acc[4][4] = {};
    for (int kb = 0; kb < 800; kb += 16) {
        #pragma unroll
        for (int e = tid; e < 1024; e += 256) {
            int kk = e >> 6, c = e & 63;
            size_t gk = (size_t)(k0 + kb + kk);
            As[kk][c] = (c < kNO) ? A[gk * kNO + c] : 0.f;
            Bs[kk][c] = Bm[gk * kNH + n0 + c];
        }
        __syncthreads();
        #pragma unroll
        for (int kk = 0; kk < 16; kk++) {
            float4 av = *(const float4*)&As[kk][ty * 4];
            float4 bv = *(const float4*)&Bs[kk][tx * 4];
            float aa[4] = {av.x, av.y, av.z, av.w};
            float bb[4] = {bv.x, bv.y, bv.z, bv.w};
            #pragma unroll
            for (int a = 0; a < 4; a++)
                #pragma unroll
                for (int c = 0; c < 4; c++) acc[a][c] += aa[a] * bb[c];
        }
        __syncthreads();
    }
    float* Cs = Cpart + (size_t)s * kNO * kNH;
    #pragma unroll
    for (int a = 0; a < 4; a++) {
        int m = ty * 4 + a;
        if (m >= kNO) continue;
        #pragma unroll
        for (int c = 0; c < 4; c++)
            Cs[(size_t)m * kNH + n0 + tx * 4 + c] = acc[a][c];
    }
}

// ---- reductions -------------------------------------------------------------
__global__ void k_reduce_gfgr(const float* __restrict__ ws, float* __restrict__ dout) {
    int idx = blockIdx.x * 256 + threadIdx.x;  // < 620544
    const int NGF = kNH * kNI, NGR = kNH * kNH;
    float s = 0.f;
    if (idx < NGF) {
        int m = idx / kNI, n = idx - m * kNI;
        size_t src = O_PGF + (size_t)m * 768 + n;
        #pragma unroll
        for (int k = 0; k < 4; k++) s += ws[src + (size_t)k * kNH * 768];
        dout[OUT_GF + idx] = s;   // LR folded into M
    } else if (idx < NGF + NGR) {
        int j = idx - NGF;
        #pragma unroll
        for (int k = 0; k < 4; k++) s += ws[O_PGR + j + (size_t)k * NGR];
        dout[OUT_GR + j] = s;
    }
}

__global__ void k_reduce_go(const float* __restrict__ ws, float* __restrict__ dout) {
    int idx = blockIdx.x * 256 + threadIdx.x;  // < 10240
    const int NGO = kNO * kNH;
    float s = 0.f;
    #pragma unroll
    for (int k = 0; k < 8; k++) s += ws[O_PGO + (size_t)k * NGO + idx];
    dout[OUT_GO + idx] = LR * s;
}

extern "C" void kernel_launch(void* const* d_in, const int* in_sizes, int n_in,
                              void* d_out, int out_size, void* d_ws, size_t ws_size,
                              hipStream_t stream) {
    (void)in_sizes; (void)n_in; (void)out_size;
    const float* x     = (const float*)d_in[0];
    const float* label = (const float*)d_in[1];
    const float* w_fc1 = (const float*)d_in[3];
    const float* w_rec = (const float*)d_in[4];
    const float* w_out = (const float*)d_in[5];
    float* out = (float*)d_out;
    float* ws  = (float*)d_ws;

    if (ws_size < WS_FLOATS * sizeof(float)) return;

    __hip_bfloat16* mtb = (__hip_bfloat16*)(ws + O_MTB);
    __hip_bfloat16* trb = (__hip_bfloat16*)(ws + O_TRB);
    __hip_bfloat16* tib = (__hip_bfloat16*)(ws + O_TIB);
    unsigned long long* gmask = (unsigned long long*)(ws + O_MSK);

    k_transpose<<<dim3(22, 16), dim3(32, 8), 0, stream>>>(w_fc1, ws + O_WT);
    k_tin<<<175, 256, 0, stream>>>(x, ws + O_TIN);
    k_xw2<<<200, 256, 0, stream>>>(x, ws + O_WT, ws + O_XW);

    k_forward<<<kB, 832, 0, stream>>>(ws, label, w_rec, w_out, out, gmask);

    k_hs_trec<<<128, 256, 0, stream>>>(ws, gmask);
    k_errscan<<<5, 256, 0, stream>>>(ws);
    k_M<<<kT * kB / 8, 256, 0, stream>>>(ws, w_out);

    // bf16 transposed-cast producers for the MFMA grad GEMMs
    k_castT<<<dim3(200, 16), dim3(32, 8), 0, stream>>>(ws + O_M,    mtb, kNH);
    k_castT<<<dim3(200, 22), dim3(32, 8), 0, stream>>>(ws + O_TIN,  tib, kNI);
    k_castT<<<dim3(200, 16), dim3(32, 8), 0, stream>>>(ws + O_TREC, trb, kNH);

    k_gemm_nt<<<96, 256, 0, stream>>>((const unsigned short*)mtb, (const unsigned short*)tib,
                                      ws + O_PGF, kNI, 768);
    k_gemm_nt<<<64, 256, 0, stream>>>((const unsigned short*)mtb, (const unsigned short*)trb,
                                      ws + O_PGR, kNH, kNH);
    k_gemmTN_go<<<64, 256, 0, stream>>>(ws + O_ERR, ws + O_HS + BNH, ws + O_PGO);

    k_reduce_gfgr<<<2424, 256, 0, stream>>>(ws, out);
    k_reduce_go<<<40, 256, 0, stream>>>(ws, out);
}